// Round 3
// baseline (717.854 us; speedup 1.0000x reference)
//
#include <hip/hip_runtime.h>

#define B_ 16
#define C_ 512
#define K_ 128
#define N_ 4096   // H*W = 64*64
#define NKEEP 51  // int(0.1 * 512)
#define NSPLIT 8  // n-reduction split for qk (8 image rows per block)

// ---------------------------------------------------------------------------
// K1: depthwise 3x3 conv (SAME, stride 1) for k and v from x_kv.
// Vectorized: each thread computes 16 consecutive pixels (quarter row) via a
// shift-register conv; float4 loads and stores.
__global__ __launch_bounds__(256) void conv_kv_kernel(const float* __restrict__ xkv,
                               const float* __restrict__ wk, const float* __restrict__ bk,
                               const float* __restrict__ wv, const float* __restrict__ bv,
                               float* __restrict__ kb, float* __restrict__ vb) {
    int idx = blockIdx.x * 256 + threadIdx.x;   // over B*K*64*4 = 524288
    int xs = (idx & 3) << 4;        // 0,16,32,48
    int y  = (idx >> 2) & 63;
    int k  = (idx >> 8) & 127;      // uniform per wave
    int b  = idx >> 15;
    const float* wkp = wk + k * 9;
    const float* wvp = wv + k * 9;
    const float* xp  = xkv + (size_t)(b * K_ + k) * N_;
    float ak[16], av[16];
    float bk0 = bk[k], bv0 = bv[k];
#pragma unroll
    for (int i = 0; i < 16; ++i) { ak[i] = bk0; av[i] = bv0; }
#pragma unroll
    for (int dy = 0; dy < 3; ++dy) {
        int yy = y + dy - 1;
        if (yy < 0 || yy > 63) continue;
        const float* row = xp + yy * 64 + xs;
        const float4* r4 = (const float4*)row;
        float4 m0 = r4[0], m1 = r4[1], m2 = r4[2], m3 = r4[3];
        float xrow[18];
        xrow[0] = (xs == 0) ? 0.f : row[-1];
        xrow[1] = m0.x;  xrow[2] = m0.y;  xrow[3] = m0.z;  xrow[4] = m0.w;
        xrow[5] = m1.x;  xrow[6] = m1.y;  xrow[7] = m1.z;  xrow[8] = m1.w;
        xrow[9] = m2.x;  xrow[10] = m2.y; xrow[11] = m2.z; xrow[12] = m2.w;
        xrow[13] = m3.x; xrow[14] = m3.y; xrow[15] = m3.z; xrow[16] = m3.w;
        xrow[17] = (xs == 48) ? 0.f : row[16];
        float ka = wkp[dy * 3], kb_ = wkp[dy * 3 + 1], kc_ = wkp[dy * 3 + 2];
        float va = wvp[dy * 3], vb_ = wvp[dy * 3 + 1], vc_ = wvp[dy * 3 + 2];
#pragma unroll
        for (int i = 0; i < 16; ++i) {
            ak[i] += xrow[i] * ka + xrow[i + 1] * kb_ + xrow[i + 2] * kc_;
            av[i] += xrow[i] * va + xrow[i + 1] * vb_ + xrow[i + 2] * vc_;
        }
    }
    size_t o = (size_t)(b * K_ + k) * N_ + y * 64 + xs;
    float4* kd = (float4*)(kb + o);
    float4* vd = (float4*)(vb + o);
#pragma unroll
    for (int m = 0; m < 4; ++m) {
        kd[m] = make_float4(ak[4*m], ak[4*m+1], ak[4*m+2], ak[4*m+3]);
        vd[m] = make_float4(av[4*m], av[4*m+1], av[4*m+2], av[4*m+3]);
    }
}

// ---------------------------------------------------------------------------
// K2: partial logits with register-prefetch pipeline.
// Block = (b, 64-channel tile, 8-image-row n-chunk).
// Per row: barrier -> pure-LDS-write stage (from regs) -> barrier ->
// issue next row's kb + xq loads -> 2048 FMAs (loads land under compute) ->
// conv math for next row from the landed regs.
__global__ __launch_bounds__(256, 3) void qk4_kernel(const float* __restrict__ xq,
                                                     const float* __restrict__ wq,
                                                     const float* __restrict__ bq,
                                                     const float* __restrict__ kb,
                                                     float* __restrict__ part) {
    __shared__ float qs[64][64];    // [n within row][c]   16 KiB
    __shared__ float ks[64][128];   // [n within row][k]   32 KiB

    // XCD-aware remap (bijective: 1024 = 8 * 128): the 8 c-tile blocks that
    // share one kb chunk land on the same XCD's L2.
    int bid = blockIdx.x;
    int blk = (bid & 7) * 128 + (bid >> 3);
    int ct  = blk & 7;              // 8 c-tiles of 64
    int ns  = (blk >> 3) & 7;       // 8 n-chunks (8 image rows each)
    int b   = blk >> 6;
    int c0  = ct * 64;
    int r0  = ns * 8;
    int tid = threadIdx.x;

    int c_l = tid >> 2;             // 0..63 (q conv channel)
    int xs  = (tid & 3) << 4;       // 0,16,32,48
    int k_l = tid >> 1;             // 0..127 (k row)
    int nh  = (tid & 1) << 5;       // 0,32
    int cg4 = (tid & 15) * 4;       // compute: c offset
    int kg8 = (tid >> 4) * 8;       // compute: k offset

    const float* wp = wq + (size_t)(c0 + c_l) * 9;
    float w00=wp[0],w01=wp[1],w02=wp[2],w10=wp[3],w11=wp[4],w12=wp[5],w20=wp[6],w21=wp[7],w22=wp[8];
    float bias = bq[c0 + c_l];
    const float* xqp = xq + ((size_t)(b * C_) + c0 + c_l) * N_;
    const float* kbp = kb + ((size_t)(b * K_) + k_l) * N_ + nh;

    // prefetch registers (all statically indexed)
    float4 kv[8];
    float4 xm[3][4];
    float  xl[3], xr[3];
    float  a16[16];

#define LOADK(r)                                                               \
    {                                                                          \
        const float4* src_ = (const float4*)(kbp + (r) * 64);                  \
        _Pragma("unroll")                                                      \
        for (int m = 0; m < 8; ++m) kv[m] = src_[m];                           \
    }

#define XLOAD(t)                                                               \
    {                                                                          \
        _Pragma("unroll")                                                      \
        for (int dy = 0; dy < 3; ++dy) {                                       \
            int yy = (t) + dy - 1;                                             \
            if (yy < 0 || yy > 63) {                                           \
                _Pragma("unroll")                                              \
                for (int m = 0; m < 4; ++m) xm[dy][m] = make_float4(0,0,0,0);  \
                xl[dy] = 0.f; xr[dy] = 0.f;                                    \
            } else {                                                           \
                const float* row_ = xqp + yy * 64 + xs;                        \
                const float4* r4_ = (const float4*)row_;                       \
                _Pragma("unroll")                                              \
                for (int m = 0; m < 4; ++m) xm[dy][m] = r4_[m];                \
                xl[dy] = (xs == 0)  ? 0.f : row_[-1];                          \
                xr[dy] = (xs == 48) ? 0.f : row_[16];                          \
            }                                                                  \
        }                                                                      \
    }

#define CONVMATH()                                                             \
    {                                                                          \
        _Pragma("unroll")                                                      \
        for (int i = 0; i < 16; ++i) a16[i] = bias;                            \
        _Pragma("unroll")                                                      \
        for (int dy = 0; dy < 3; ++dy) {                                       \
            float wa = (dy == 0) ? w00 : (dy == 1) ? w10 : w20;                \
            float wb = (dy == 0) ? w01 : (dy == 1) ? w11 : w21;                \
            float wc = (dy == 0) ? w02 : (dy == 1) ? w12 : w22;                \
            float xrow[18];                                                    \
            xrow[0] = xl[dy];                                                  \
            _Pragma("unroll")                                                  \
            for (int m = 0; m < 4; ++m) {                                      \
                xrow[1 + 4*m] = xm[dy][m].x; xrow[2 + 4*m] = xm[dy][m].y;      \
                xrow[3 + 4*m] = xm[dy][m].z; xrow[4 + 4*m] = xm[dy][m].w;      \
            }                                                                  \
            xrow[17] = xr[dy];                                                 \
            _Pragma("unroll")                                                  \
            for (int i = 0; i < 16; ++i)                                       \
                a16[i] += xrow[i] * wa + xrow[i + 1] * wb + xrow[i + 2] * wc;  \
        }                                                                      \
    }

    float acc[4][8];
#pragma unroll
    for (int i = 0; i < 4; ++i)
#pragma unroll
        for (int j = 0; j < 8; ++j) acc[i][j] = 0.f;

    // prologue: row r0 fully prepared in registers
    LOADK(r0);
    XLOAD(r0);
    CONVMATH();

    for (int rr = 0; rr < 8; ++rr) {
        __syncthreads();            // previous row's compute done, LDS free
        // ---- stage = pure LDS writes from registers ----
#pragma unroll
        for (int m = 0; m < 8; ++m) {
            int nn = nh + m * 4;
            ks[nn][k_l]     = kv[m].x; ks[nn + 1][k_l] = kv[m].y;
            ks[nn + 2][k_l] = kv[m].z; ks[nn + 3][k_l] = kv[m].w;
        }
#pragma unroll
        for (int i = 0; i < 16; ++i) qs[xs + i][c_l] = a16[i];
        __syncthreads();
        // ---- issue next row's loads; they land under the FMAs ----
        if (rr < 7) { LOADK(r0 + rr + 1); XLOAD(r0 + rr + 1); }
        // ---- accumulate 4c x 8k outer products over this row ----
#pragma unroll 4
        for (int nn = 0; nn < 64; ++nn) {
            float4 q4  = *(const float4*)&qs[nn][cg4];
            float4 k4a = *(const float4*)&ks[nn][kg8];
            float4 k4b = *(const float4*)&ks[nn][kg8 + 4];
            float qa[4] = {q4.x, q4.y, q4.z, q4.w};
            float kk[8] = {k4a.x, k4a.y, k4a.z, k4a.w, k4b.x, k4b.y, k4b.z, k4b.w};
#pragma unroll
            for (int i = 0; i < 4; ++i)
#pragma unroll
                for (int j = 0; j < 8; ++j) acc[i][j] += qa[i] * kk[j];
        }
        // ---- conv math for next row, from regs (loads have drained) ----
        if (rr < 7) CONVMATH();
    }
#undef LOADK
#undef XLOAD
#undef CONVMATH

    // write partials: part[ns][b][c][k]
    float* dst = part + (((size_t)ns * B_ + b) * C_ + c0 + cg4) * K_ + kg8;
#pragma unroll
    for (int i = 0; i < 4; ++i) {
        *(float4*)(dst + (size_t)i * K_)     = make_float4(acc[i][0], acc[i][1], acc[i][2], acc[i][3]);
        *(float4*)(dst + (size_t)i * K_ + 4) = make_float4(acc[i][4], acc[i][5], acc[i][6], acc[i][7]);
    }
}

// ---------------------------------------------------------------------------
// K3: reduce NSPLIT partials, scale by 1/sqrt(128), softmax over k (128)
// per (b,c) row. One wave per row.
__global__ void softmax_kernel(const float* __restrict__ part, float* __restrict__ aw) {
    int tid  = threadIdx.x;
    int wave = tid >> 6;
    int lane = tid & 63;
    int row  = blockIdx.x * 4 + wave;   // over B*C = 8192
    float v0 = 0.f, v1 = 0.f;
#pragma unroll
    for (int ns = 0; ns < NSPLIT; ++ns) {
        const float* p = part + ((size_t)ns * B_ * C_ + row) * K_;
        v0 += p[lane];
        v1 += p[lane + 64];
    }
    const float scale = 0.08838834764831845f; // 1/sqrt(128)
    v0 *= scale; v1 *= scale;
    float m = fmaxf(v0, v1);
#pragma unroll
    for (int s = 32; s >= 1; s >>= 1) m = fmaxf(m, __shfl_xor(m, s, 64));
    float e0 = __expf(v0 - m), e1 = __expf(v1 - m);
    float s = e0 + e1;
#pragma unroll
    for (int t = 32; t >= 1; t >>= 1) s += __shfl_xor(s, t, 64);
    float inv = 1.0f / s;
    float* q = aw + (size_t)row * K_;
    q[lane] = e0 * inv;
    q[lane + 64] = e1 * inv;
}

// ---------------------------------------------------------------------------
// K4: per (b,k) column over c (512): find 51st-largest exactly via binary
// search on float bit pattern (positive floats order as uints), zero the rest.
__global__ void topk_mask_kernel(float* __restrict__ aw) {
    int tid  = threadIdx.x;
    int wave = tid >> 6, lane = tid & 63;
    int col  = blockIdx.x * 4 + wave;   // over B*K = 2048
    int b = col >> 7, k = col & 127;
    float* base = aw + (size_t)(b * C_) * K_ + k;
    unsigned u[8];
#pragma unroll
    for (int j = 0; j < 8; ++j)
        u[j] = __float_as_uint(base[(size_t)(j * 64 + lane) * K_]);
    unsigned T = 0;
#pragma unroll
    for (int bit = 31; bit >= 0; --bit) {
        unsigned cand = T | (1u << bit);
        int cnt = 0;
#pragma unroll
        for (int j = 0; j < 8; ++j) cnt += (u[j] >= cand) ? 1 : 0;
#pragma unroll
        for (int s = 32; s >= 1; s >>= 1) cnt += __shfl_xor(cnt, s, 64);
        if (cnt >= NKEEP) T = cand;
    }
#pragma unroll
    for (int j = 0; j < 8; ++j)
        if (u[j] < T) base[(size_t)(j * 64 + lane) * K_] = 0.0f;
}

// ---------------------------------------------------------------------------
// K5: attn_out = aw_masked @ v ; out0 = x_q + attn_out.
// Block tile: 32 c x 256 n, inner k chunked by 16, register-prefetch pipeline.
// __launch_bounds__(256,3): cap ~170 VGPR so the prefetch regs do NOT spill
// to scratch (r2: VGPR=44 with ~70 live -> 400 MB of scratch write traffic).
__global__ __launch_bounds__(256, 3) void av_kernel(const float* __restrict__ aw,
                                                 const float* __restrict__ vb,
                                                 const float* __restrict__ xq,
                                                 float* __restrict__ out) {
    __shared__ float vs[16][260];   // [k][n], pad 256->260
    __shared__ float aws[16][36];   // [k][c], pad 32->36
    int blk  = blockIdx.x;
    int b    = blk >> 8;
    int rest = blk & 255;
    int c0 = (rest >> 4) * 32;
    int n0 = (rest & 15) * 256;
    int tid = threadIdx.x;
    int cg = tid >> 5;              // 0..7, cbase = cg*4
    int ng = tid & 31;              // nbase = ng*8
    int k_l = tid >> 4;             // 0..15 (vs staging row)
    int nn0 = (tid & 15) * 16;
    int i0  = tid * 2;
    int cc0 = i0 >> 4,       kk0 = i0 & 15;
    int cc1 = (i0 + 1) >> 4, kk1 = (i0 + 1) & 15;

    float4 vv[4];
    float  a0, a1;

#define LOADAV(kc)                                                              \
    {                                                                           \
        const float4* src = (const float4*)(vb + (size_t)(b * K_ + (kc) + k_l) * N_ + n0 + nn0); \
        _Pragma("unroll")                                                       \
        for (int m = 0; m < 4; ++m) vv[m] = src[m];                             \
        a0 = aw[(size_t)(b * C_ + c0 + cc0) * K_ + (kc) + kk0];                 \
        a1 = aw[(size_t)(b * C_ + c0 + cc1) * K_ + (kc) + kk1];                 \
    }

    float acc[4][8];
#pragma unroll
    for (int i = 0; i < 4; ++i)
#pragma unroll
        for (int j = 0; j < 8; ++j) acc[i][j] = 0.f;

    LOADAV(0);

    for (int kc = 0; kc < K_; kc += 16) {
        __syncthreads();
        // stage from prefetched regs
        {
            float4* dst = (float4*)&vs[k_l][nn0];
#pragma unroll
            for (int m = 0; m < 4; ++m) dst[m] = vv[m];
            aws[kk0][cc0] = a0;
            aws[kk1][cc1] = a1;
        }
        __syncthreads();
        // issue next chunk's loads; they land under the FMAs
        if (kc + 16 < K_) LOADAV(kc + 16);
#pragma unroll
        for (int kk = 0; kk < 16; ++kk) {
            float4 a4  = *(const float4*)&aws[kk][cg * 4];
            float4 v4a = *(const float4*)&vs[kk][ng * 8];
            float4 v4b = *(const float4*)&vs[kk][ng * 8 + 4];
            float aa[4] = {a4.x, a4.y, a4.z, a4.w};
            float av[8] = {v4a.x, v4a.y, v4a.z, v4a.w, v4b.x, v4b.y, v4b.z, v4b.w};
#pragma unroll
            for (int i = 0; i < 4; ++i)
#pragma unroll
                for (int j = 0; j < 8; ++j) acc[i][j] += aa[i] * av[j];
        }
    }
#undef LOADAV

    // epilogue: out = x_q + acc, vectorized
#pragma unroll
    for (int i = 0; i < 4; ++i) {
        int c = c0 + cg * 4 + i;
        size_t base = (size_t)(b * C_ + c) * N_ + n0 + ng * 8;
        const float4* xp4 = (const float4*)(xq + base);
        float4* op4 = (float4*)(out + base);
        float4 x0 = xp4[0], x1 = xp4[1];
        float4 o0, o1;
        o0.x = x0.x + acc[i][0]; o0.y = x0.y + acc[i][1];
        o0.z = x0.z + acc[i][2]; o0.w = x0.w + acc[i][3];
        o1.x = x1.x + acc[i][4]; o1.y = x1.y + acc[i][5];
        o1.z = x1.z + acc[i][6]; o1.w = x1.w + acc[i][7];
        op4[0] = o0; op4[1] = o1;
    }
}

// ---------------------------------------------------------------------------
extern "C" void kernel_launch(void* const* d_in, const int* in_sizes, int n_in,
                              void* d_out, int out_size, void* d_ws, size_t ws_size,
                              hipStream_t stream) {
    const float* xq  = (const float*)d_in[0];
    const float* xkv = (const float*)d_in[1];
    const float* wq  = (const float*)d_in[2];
    const float* bq  = (const float*)d_in[3];
    const float* wk  = (const float*)d_in[4];
    const float* bk  = (const float*)d_in[5];
    const float* wv  = (const float*)d_in[6];
    const float* bv  = (const float*)d_in[7];

    float* out0 = (float*)d_out;                       // [16,512,64,64]
    float* aw   = out0 + (size_t)B_ * C_ * N_;         // [16,512,128]

    float* kb = (float*)d_ws;                          // [16,128,4096]
    float* vb = kb + (size_t)B_ * K_ * N_;             // [16,128,4096]
    // qk partials scratch: reuse out0's memory (33.5 MB of its 134 MB);
    // K5 fully overwrites out0 afterwards and never reads it.
    float* part = out0;                                // [NSPLIT][16][512][128]

    // 1. depthwise conv for k, v (16 px/thread, vectorized)
    conv_kv_kernel<<<(B_ * K_ * 64 * 4) / 256, 256, 0, stream>>>(xkv, wk, bk, wv, bv, kb, vb);
    // 2. partial logits, q conv fused; register-prefetch pipeline + XCD swizzle
    qk4_kernel<<<B_ * 64, 256, 0, stream>>>(xq, wq, bq, kb, part);
    // 3. reduce partials + scale + softmax over k
    softmax_kernel<<<(B_ * C_) / 4, 256, 0, stream>>>(part, aw);
    // 4. top-51 along c per (b,k), mask in place
    topk_mask_kernel<<<(B_ * K_) / 4, 256, 0, stream>>>(aw);
    // 5. attn_out = aw @ v + x_q
    av_kernel<<<B_ * 256, 256, 0, stream>>>(aw, vb, xq, out0);
}

// Round 4
// 531.703 us; speedup vs baseline: 1.3501x; 1.3501x over previous
//
#include <hip/hip_runtime.h>

#define B_ 16
#define C_ 512
#define K_ 128
#define N_ 4096   // H*W = 64*64
#define NKEEP 51  // int(0.1 * 512)
#define NSPLIT 16 // n-reduction split for qk (4 image rows per block)

// ---------------------------------------------------------------------------
// K1: depthwise 3x3 conv (SAME, stride 1) for k and v from x_kv.
// Vectorized: each thread computes 16 consecutive pixels (quarter row) via a
// shift-register conv; float4 loads and stores.
__global__ __launch_bounds__(256) void conv_kv_kernel(const float* __restrict__ xkv,
                               const float* __restrict__ wk, const float* __restrict__ bk,
                               const float* __restrict__ wv, const float* __restrict__ bv,
                               float* __restrict__ kb, float* __restrict__ vb) {
    int idx = blockIdx.x * 256 + threadIdx.x;   // over B*K*64*4 = 524288
    int xs = (idx & 3) << 4;        // 0,16,32,48
    int y  = (idx >> 2) & 63;
    int k  = (idx >> 8) & 127;      // uniform per wave
    int b  = idx >> 15;
    const float* wkp = wk + k * 9;
    const float* wvp = wv + k * 9;
    const float* xp  = xkv + (size_t)(b * K_ + k) * N_;
    float ak[16], av[16];
    float bk0 = bk[k], bv0 = bv[k];
#pragma unroll
    for (int i = 0; i < 16; ++i) { ak[i] = bk0; av[i] = bv0; }
#pragma unroll
    for (int dy = 0; dy < 3; ++dy) {
        int yy = y + dy - 1;
        if (yy < 0 || yy > 63) continue;
        const float* row = xp + yy * 64 + xs;
        const float4* r4 = (const float4*)row;
        float4 m0 = r4[0], m1 = r4[1], m2 = r4[2], m3 = r4[3];
        float xrow[18];
        xrow[0] = (xs == 0) ? 0.f : row[-1];
        xrow[1] = m0.x;  xrow[2] = m0.y;  xrow[3] = m0.z;  xrow[4] = m0.w;
        xrow[5] = m1.x;  xrow[6] = m1.y;  xrow[7] = m1.z;  xrow[8] = m1.w;
        xrow[9] = m2.x;  xrow[10] = m2.y; xrow[11] = m2.z; xrow[12] = m2.w;
        xrow[13] = m3.x; xrow[14] = m3.y; xrow[15] = m3.z; xrow[16] = m3.w;
        xrow[17] = (xs == 48) ? 0.f : row[16];
        float ka = wkp[dy * 3], kb_ = wkp[dy * 3 + 1], kc_ = wkp[dy * 3 + 2];
        float va = wvp[dy * 3], vb_ = wvp[dy * 3 + 1], vc_ = wvp[dy * 3 + 2];
#pragma unroll
        for (int i = 0; i < 16; ++i) {
            ak[i] += xrow[i] * ka + xrow[i + 1] * kb_ + xrow[i + 2] * kc_;
            av[i] += xrow[i] * va + xrow[i + 1] * vb_ + xrow[i + 2] * vc_;
        }
    }
    size_t o = (size_t)(b * K_ + k) * N_ + y * 64 + xs;
    float4* kd = (float4*)(kb + o);
    float4* vd = (float4*)(vb + o);
#pragma unroll
    for (int m = 0; m < 4; ++m) {
        kd[m] = make_float4(ak[4*m], ak[4*m+1], ak[4*m+2], ak[4*m+3]);
        vd[m] = make_float4(av[4*m], av[4*m+1], av[4*m+2], av[4*m+3]);
    }
}

// ---------------------------------------------------------------------------
// K2: partial logits. Block = (b, 64-channel tile, 4-image-row n-chunk).
// part[ns][b][c][k] = sum over the chunk's 256 n of q[b,c,n]*k[b,k,n]
// q is computed on the fly (depthwise conv on x_q) during staging.
// Identical inner code to the 178-us qk2 (VGPR 68, no spill); only the
// n-chunking changed (8 rows -> 4) to double the grid and shrink the
// dispatch tail (observed occupancy 23.7% vs 37.5% LDS-bound ceiling).
__global__ __launch_bounds__(256) void qk5_kernel(const float* __restrict__ xq,
                                                  const float* __restrict__ wq,
                                                  const float* __restrict__ bq,
                                                  const float* __restrict__ kb,
                                                  float* __restrict__ part) {
    __shared__ float qs[64][64];    // [n within row][c]   16 KiB
    __shared__ float ks[64][128];   // [n within row][k]   32 KiB
    int blk = blockIdx.x;
    int ct  = blk & 7;              // 8 c-tiles of 64
    int ns  = (blk >> 3) & 15;      // 16 n-chunks (4 image rows each)
    int b   = blk >> 7;
    int c0  = ct * 64;
    int r0  = ns * 4;
    int tid = threadIdx.x;

    // conv staging role: channel c_l, 16-pixel x-segment
    int c_l = tid >> 2;             // 0..63
    int xs  = (tid & 3) << 4;       // 0,16,32,48
    // k staging role: k-row, 32-pixel half
    int k_l = tid >> 1;             // 0..127
    int nh  = (tid & 1) << 5;       // 0,32
    // compute role: 16 c-groups x 16 k-groups
    int cg4 = (tid & 15) * 4;       // c offset within tile
    int kg8 = (tid >> 4) * 8;       // k offset

    // preload conv weights for channel c0+c_l
    const float* wp = wq + (size_t)(c0 + c_l) * 9;
    float w00=wp[0],w01=wp[1],w02=wp[2],w10=wp[3],w11=wp[4],w12=wp[5],w20=wp[6],w21=wp[7],w22=wp[8];
    float bias = bq[c0 + c_l];
    const float* xqp = xq + ((size_t)(b * C_) + c0 + c_l) * N_;
    const float* kbp = kb + ((size_t)(b * K_) + k_l) * N_;

    float acc[4][8];
#pragma unroll
    for (int i = 0; i < 4; ++i)
#pragma unroll
        for (int j = 0; j < 8; ++j) acc[i][j] = 0.f;

    for (int rr = 0; rr < 4; ++rr) {
        int r = r0 + rr;
        __syncthreads();
        // ---- stage ks[n][k]: row r of k-plane k_l (2-way write, free) ----
        {
            const float4* src = (const float4*)(kbp + r * 64 + nh);
#pragma unroll
            for (int m = 0; m < 8; ++m) {
                float4 v = src[m];
                int nn = nh + m * 4;
                ks[nn][k_l] = v.x; ks[nn + 1][k_l] = v.y;
                ks[nn + 2][k_l] = v.z; ks[nn + 3][k_l] = v.w;
            }
        }
        // ---- stage qs[n][c]: conv on the fly, 16 pixels of row r, ch c_l ----
        {
            float a16[16];
#pragma unroll
            for (int i = 0; i < 16; ++i) a16[i] = bias;
#pragma unroll
            for (int dy = 0; dy < 3; ++dy) {
                int yy = r + dy - 1;
                if (yy < 0 || yy > 63) continue;
                const float* row = xqp + yy * 64;
                float wa = (dy == 0) ? w00 : (dy == 1) ? w10 : w20;
                float wb = (dy == 0) ? w01 : (dy == 1) ? w11 : w21;
                float wc = (dy == 0) ? w02 : (dy == 1) ? w12 : w22;
                float p = (xs == 0) ? 0.f : row[xs - 1];
                float c = row[xs];
#pragma unroll
                for (int i = 0; i < 16; ++i) {
                    int x = xs + i;
                    float n = (x == 63) ? 0.f : row[x + 1];
                    a16[i] += p * wa + c * wb + n * wc;
                    p = c; c = n;
                }
            }
#pragma unroll
            for (int i = 0; i < 16; ++i) qs[xs + i][c_l] = a16[i];
        }
        __syncthreads();
        // ---- accumulate 4c x 8k outer products over this row ----
#pragma unroll 4
        for (int nn = 0; nn < 64; ++nn) {
            float4 q4  = *(const float4*)&qs[nn][cg4];
            float4 k4a = *(const float4*)&ks[nn][kg8];
            float4 k4b = *(const float4*)&ks[nn][kg8 + 4];
            float qa[4] = {q4.x, q4.y, q4.z, q4.w};
            float kk[8] = {k4a.x, k4a.y, k4a.z, k4a.w, k4b.x, k4b.y, k4b.z, k4b.w};
#pragma unroll
            for (int i = 0; i < 4; ++i)
#pragma unroll
                for (int j = 0; j < 8; ++j) acc[i][j] += qa[i] * kk[j];
        }
    }
    // write partials: part[ns][b][c][k]
    float* dst = part + (((size_t)ns * B_ + b) * C_ + c0 + cg4) * K_ + kg8;
#pragma unroll
    for (int i = 0; i < 4; ++i) {
        *(float4*)(dst + (size_t)i * K_)     = make_float4(acc[i][0], acc[i][1], acc[i][2], acc[i][3]);
        *(float4*)(dst + (size_t)i * K_ + 4) = make_float4(acc[i][4], acc[i][5], acc[i][6], acc[i][7]);
    }
}

// ---------------------------------------------------------------------------
// K3: reduce NSPLIT partials, scale by 1/sqrt(128), softmax over k (128)
// per (b,c) row. One wave per row.
__global__ void softmax_kernel(const float* __restrict__ part, float* __restrict__ aw) {
    int tid  = threadIdx.x;
    int wave = tid >> 6;
    int lane = tid & 63;
    int row  = blockIdx.x * 4 + wave;   // over B*C = 8192
    float v0 = 0.f, v1 = 0.f;
#pragma unroll
    for (int ns = 0; ns < NSPLIT; ++ns) {
        const float* p = part + ((size_t)ns * B_ * C_ + row) * K_;
        v0 += p[lane];
        v1 += p[lane + 64];
    }
    const float scale = 0.08838834764831845f; // 1/sqrt(128)
    v0 *= scale; v1 *= scale;
    float m = fmaxf(v0, v1);
#pragma unroll
    for (int s = 32; s >= 1; s >>= 1) m = fmaxf(m, __shfl_xor(m, s, 64));
    float e0 = __expf(v0 - m), e1 = __expf(v1 - m);
    float s = e0 + e1;
#pragma unroll
    for (int t = 32; t >= 1; t >>= 1) s += __shfl_xor(s, t, 64);
    float inv = 1.0f / s;
    float* q = aw + (size_t)row * K_;
    q[lane] = e0 * inv;
    q[lane + 64] = e1 * inv;
}

// ---------------------------------------------------------------------------
// K4: per (b,k) column over c (512): find 51st-largest exactly via binary
// search on float bit pattern (positive floats order as uints), zero the rest.
__global__ void topk_mask_kernel(float* __restrict__ aw) {
    int tid  = threadIdx.x;
    int wave = tid >> 6, lane = tid & 63;
    int col  = blockIdx.x * 4 + wave;   // over B*K = 2048
    int b = col >> 7, k = col & 127;
    float* base = aw + (size_t)(b * C_) * K_ + k;
    unsigned u[8];
#pragma unroll
    for (int j = 0; j < 8; ++j)
        u[j] = __float_as_uint(base[(size_t)(j * 64 + lane) * K_]);
    unsigned T = 0;
#pragma unroll
    for (int bit = 31; bit >= 0; --bit) {
        unsigned cand = T | (1u << bit);
        int cnt = 0;
#pragma unroll
        for (int j = 0; j < 8; ++j) cnt += (u[j] >= cand) ? 1 : 0;
#pragma unroll
        for (int s = 32; s >= 1; s >>= 1) cnt += __shfl_xor(cnt, s, 64);
        if (cnt >= NKEEP) T = cand;
    }
#pragma unroll
    for (int j = 0; j < 8; ++j)
        if (u[j] < T) base[(size_t)(j * 64 + lane) * K_] = 0.0f;
}

// ---------------------------------------------------------------------------
// K5: attn_out = aw_masked @ v ; out0 = x_q + attn_out.
// Round-1 original: no prefetch regs. 19 KB LDS -> 8 blocks/CU, and the
// compiler fits VGPR <= 64 so all 32 wave slots fill; TLP hides the stage
// latency (rounds 2-3 prefetch variants spilled and regressed).
__global__ __launch_bounds__(256) void av_kernel(const float* __restrict__ aw,
                                                 const float* __restrict__ vb,
                                                 const float* __restrict__ xq,
                                                 float* __restrict__ out) {
    __shared__ float vs[16][260];   // [k][n], pad 256->260
    __shared__ float aws[16][36];   // [k][c], pad 32->36
    int blk  = blockIdx.x;
    int b    = blk >> 8;
    int rest = blk & 255;
    int c0 = (rest >> 4) * 32;
    int n0 = (rest & 15) * 256;
    int tid = threadIdx.x;
    int cg = tid >> 5;              // 0..7, cbase = cg*4
    int ng = tid & 31;              // nbase = ng*8
    int k_l = tid >> 4;             // 0..15 (vs staging row)
    int nn0 = (tid & 15) * 16;

    float acc[4][8];
#pragma unroll
    for (int i = 0; i < 4; ++i)
#pragma unroll
        for (int j = 0; j < 8; ++j) acc[i][j] = 0.f;

    for (int kc = 0; kc < K_; kc += 16) {
        __syncthreads();
        // stage vs[k][n]: natural layout, float4
        {
            const float4* src = (const float4*)(vb + (size_t)(b * K_ + kc + k_l) * N_ + n0 + nn0);
            float4* dst = (float4*)&vs[k_l][nn0];
#pragma unroll
            for (int m = 0; m < 4; ++m) dst[m] = src[m];
        }
        // stage aws transposed: [k][c]
        {
            int i0 = tid * 2;
#pragma unroll
            for (int t2 = 0; t2 < 2; ++t2) {
                int i = i0 + t2;
                int cc = i >> 4;    // 0..31
                int kk = i & 15;
                aws[kk][cc] = aw[(size_t)(b * C_ + c0 + cc) * K_ + kc + kk];
            }
        }
        __syncthreads();
#pragma unroll
        for (int kk = 0; kk < 16; ++kk) {
            float4 a4  = *(const float4*)&aws[kk][cg * 4];
            float4 v4a = *(const float4*)&vs[kk][ng * 8];
            float4 v4b = *(const float4*)&vs[kk][ng * 8 + 4];
            float aa[4] = {a4.x, a4.y, a4.z, a4.w};
            float av[8] = {v4a.x, v4a.y, v4a.z, v4a.w, v4b.x, v4b.y, v4b.z, v4b.w};
#pragma unroll
            for (int i = 0; i < 4; ++i)
#pragma unroll
                for (int j = 0; j < 8; ++j) acc[i][j] += aa[i] * av[j];
        }
    }
    // epilogue: out = x_q + acc, vectorized
#pragma unroll
    for (int i = 0; i < 4; ++i) {
        int c = c0 + cg * 4 + i;
        size_t base = (size_t)(b * C_ + c) * N_ + n0 + ng * 8;
        const float4* xp4 = (const float4*)(xq + base);
        float4* op4 = (float4*)(out + base);
        float4 x0 = xp4[0], x1 = xp4[1];
        float4 o0, o1;
        o0.x = x0.x + acc[i][0]; o0.y = x0.y + acc[i][1];
        o0.z = x0.z + acc[i][2]; o0.w = x0.w + acc[i][3];
        o1.x = x1.x + acc[i][4]; o1.y = x1.y + acc[i][5];
        o1.z = x1.z + acc[i][6]; o1.w = x1.w + acc[i][7];
        op4[0] = o0; op4[1] = o1;
    }
}

// ---------------------------------------------------------------------------
extern "C" void kernel_launch(void* const* d_in, const int* in_sizes, int n_in,
                              void* d_out, int out_size, void* d_ws, size_t ws_size,
                              hipStream_t stream) {
    const float* xq  = (const float*)d_in[0];
    const float* xkv = (const float*)d_in[1];
    const float* wq  = (const float*)d_in[2];
    const float* bq  = (const float*)d_in[3];
    const float* wk  = (const float*)d_in[4];
    const float* bk  = (const float*)d_in[5];
    const float* wv  = (const float*)d_in[6];
    const float* bv  = (const float*)d_in[7];

    float* out0 = (float*)d_out;                       // [16,512,64,64]
    float* aw   = out0 + (size_t)B_ * C_ * N_;         // [16,512,128]

    float* kb = (float*)d_ws;                          // [16,128,4096]
    float* vb = kb + (size_t)B_ * K_ * N_;             // [16,128,4096]
    // qk partials scratch: reuse out0's memory (67 MB of its 134 MB);
    // K5 fully overwrites out0 afterwards and never reads it.
    float* part = out0;                                // [NSPLIT][16][512][128]

    // 1. depthwise conv for k, v (16 px/thread, vectorized)
    conv_kv_kernel<<<(B_ * K_ * 64 * 4) / 256, 256, 0, stream>>>(xkv, wk, bk, wv, bv, kb, vb);
    // 2. partial logits, q conv fused; 16b x 16 n-chunks x 8 c-tiles
    qk5_kernel<<<B_ * 128, 256, 0, stream>>>(xq, wq, bq, kb, part);
    // 3. reduce partials + scale + softmax over k
    softmax_kernel<<<(B_ * C_) / 4, 256, 0, stream>>>(part, aw);
    // 4. top-51 along c per (b,k), mask in place
    topk_mask_kernel<<<(B_ * K_) / 4, 256, 0, stream>>>(aw);
    // 5. attn_out = aw @ v + x_q
    av_kernel<<<B_ * 256, 256, 0, stream>>>(aw, vb, xq, out0);
}